// Round 18
// baseline (578.969 us; speedup 1.0000x reference)
//
#include <hip/hip_runtime.h>
#include <hip/hip_bf16.h>

// GraphStack: 3x (GCNConv -> GraphNorm), N=100000, E=3.2M, D_IN=128, C=64.
//
// Round 18:
//  - Channel-sliced gather tables: xws/hb stored as 4 slices [N][16] bf16
//    (3.2MB each, fits per-XCD 4MB L2). k_pull loops slices in-kernel: per
//    edge per slice a 4B gather (2ch/lane) -> gathers become L2 hits
//    (r17 pull: 165MB L2-miss vs 422MB logical = the 12.8MB table thrashing
//    4MB L2). Pure layout change: arithmetic bit-identical.
//  - gemm_mfma reads/writes sliced (A-frag 16B loads still contiguous).
//  - Rest identical to round 17 (MFMA gemms, scan ELL build, k_params2).
//
// d_out (N*64 f32) is the final agg buffer.

#define EPS 1e-5f

typedef __attribute__((ext_vector_type(8))) short bf16x8;
typedef __attribute__((ext_vector_type(4))) float f32x4;

__device__ __forceinline__ float bf_lo(unsigned u) {
    union { unsigned u; float f; } c; c.u = u << 16; return c.f;
}
__device__ __forceinline__ float bf_hi(unsigned u) {
    union { unsigned u; float f; } c; c.u = u & 0xffff0000u; return c.f;
}
__device__ __forceinline__ unsigned pack_bf2(float a, float b) {
    union { __hip_bfloat16 h; unsigned short u; } ca, cb;
    ca.h = __float2bfloat16(a);
    cb.h = __float2bfloat16(b);
    return (unsigned)ca.u | ((unsigned)cb.u << 16);
}
__device__ __forceinline__ short bfb(float f) {
    union { __hip_bfloat16 h; short s; } u; u.h = __float2bfloat16(f); return u.s;
}

// ================= scan-based ELL build =================
__global__ __launch_bounds__(256) void k_hist(const int* __restrict__ dst, int* __restrict__ hist,
                                              int E, int SEG, int NBKT) {
    __shared__ int h[2048];
    int t = threadIdx.x;
    for (int b = t; b < NBKT; b += 256) h[b] = 0;
    __syncthreads();
    int i0 = blockIdx.x * SEG, i1 = min(E, i0 + SEG);
    for (int i = i0 + t * 4; i < i1; i += 1024) {
        if (i + 3 < i1) {
            int4 d = *(const int4*)(dst + i);
            atomicAdd(&h[d.x >> 6], 1);
            atomicAdd(&h[d.y >> 6], 1);
            atomicAdd(&h[d.z >> 6], 1);
            atomicAdd(&h[d.w >> 6], 1);
        } else {
            for (int q = i; q < i1; ++q) atomicAdd(&h[dst[q] >> 6], 1);
        }
    }
    __syncthreads();
    for (int b = t; b < NBKT; b += 256) hist[blockIdx.x * NBKT + b] = h[b];
}

__global__ __launch_bounds__(256) void k_scanA(const int* __restrict__ hist, int* __restrict__ chunkScan,
                                               int* __restrict__ chunkTot, int NBKT, int SCAN_N) {
    __shared__ int ls[256];
    int t = threadIdx.x;
    int base = blockIdx.x * 1024 + t * 4;
    int v[4];
#pragma unroll
    for (int j = 0; j < 4; ++j) {
        int l = base + j;
        v[j] = 0;
        if (l < SCAN_N) {
            int blk = l & 255, bkt = l >> 8;
            v[j] = hist[blk * NBKT + bkt];
        }
    }
    int s = v[0] + v[1] + v[2] + v[3];
    ls[t] = s;
    __syncthreads();
    for (int off = 1; off < 256; off <<= 1) {
        int val = (t >= off) ? ls[t - off] : 0;
        __syncthreads();
        ls[t] += val;
        __syncthreads();
    }
    int run = ls[t] - s;
#pragma unroll
    for (int j = 0; j < 4; ++j) {
        chunkScan[base + j] = run;
        run += v[j];
    }
    if (t == 255) chunkTot[blockIdx.x] = ls[255];
}

__global__ void k_scanB(const int* __restrict__ chunkTot, int* __restrict__ chunkBase, int NCH) {
    __shared__ int s[512];
    int t = threadIdx.x;
    s[t] = (t < NCH) ? chunkTot[t] : 0;
    s[t + 256] = (t + 256 < NCH) ? chunkTot[t + 256] : 0;
    __syncthreads();
    for (int off = 1; off < 512; off <<= 1) {
        int a0 = (t >= off) ? s[t - off] : 0;
        int a1 = (t + 256 >= off) ? s[t + 256 - off] : 0;
        __syncthreads();
        s[t] += a0;
        s[t + 256] += a1;
        __syncthreads();
    }
    if (t < NCH) chunkBase[t] = t ? s[t - 1] : 0;
    if (t + 256 < NCH) chunkBase[t + 256] = s[t + 255];
}

__global__ __launch_bounds__(256) void k_scatter_part(const int* __restrict__ src, const int* __restrict__ dst,
                                                      const int* __restrict__ chunkScan,
                                                      const int* __restrict__ chunkBase,
                                                      int* __restrict__ packed, int E, int SEG, int NBKT) {
    __shared__ int cur[2048];
    int blk = blockIdx.x, t = threadIdx.x;
    for (int b = t; b < NBKT; b += 256) {
        int l = b * 256 + blk;
        cur[b] = chunkScan[l] + chunkBase[l >> 10];
    }
    __syncthreads();
    int i0 = blk * SEG, i1 = min(E, i0 + SEG);
    for (int i = i0 + t * 4; i < i1; i += 1024) {
        if (i + 3 < i1) {
            int4 d = *(const int4*)(dst + i);
            int4 s = *(const int4*)(src + i);
            int p;
            p = atomicAdd(&cur[d.x >> 6], 1); packed[p] = (int)(((unsigned)(d.x & 63) << 26) | (unsigned)s.x);
            p = atomicAdd(&cur[d.y >> 6], 1); packed[p] = (int)(((unsigned)(d.y & 63) << 26) | (unsigned)s.y);
            p = atomicAdd(&cur[d.z >> 6], 1); packed[p] = (int)(((unsigned)(d.z & 63) << 26) | (unsigned)s.z);
            p = atomicAdd(&cur[d.w >> 6], 1); packed[p] = (int)(((unsigned)(d.w & 63) << 26) | (unsigned)s.w);
        } else {
            for (int q = i; q < i1; ++q) {
                int dd = dst[q];
                int p = atomicAdd(&cur[dd >> 6], 1);
                packed[p] = (int)(((unsigned)(dd & 63) << 26) | (unsigned)src[q]);
            }
        }
    }
}

__global__ __launch_bounds__(256) void k_ellfill(const int* __restrict__ packed,
                                                 const int* __restrict__ chunkScan,
                                                 const int* __restrict__ chunkBase,
                                                 int* __restrict__ ell, int* __restrict__ cursor,
                                                 float* __restrict__ dinv,
                                                 int CAP, int NBKT, int N, int E) {
    __shared__ int ellLoc[64 * 96];
    __shared__ int cnt[64];
    int bkt = blockIdx.x, t = threadIdx.x;
    if (t < 64) cnt[t] = 0;
    __syncthreads();
    int l0 = bkt * 256;
    int bs = chunkScan[l0] + chunkBase[l0 >> 10];
    int be = E;
    if (bkt + 1 < NBKT) {
        int l1 = (bkt + 1) * 256;
        be = chunkScan[l1] + chunkBase[l1 >> 10];
    }
    for (int i = bs + t; i < be; i += 256) {
        unsigned p = (unsigned)packed[i];
        int s = (int)(p & 0x03FFFFFFu);
        int ld = (int)(p >> 26);
        int slot = atomicAdd(&cnt[ld], 1);
        if (slot < CAP) ellLoc[ld * CAP + slot] = s;
    }
    __syncthreads();
    int lo = bkt << 6;
    int total = 64 * CAP;
    for (int idx = t; idx < total; idx += 256) {
        int ld = idx / CAP;
        int s = idx - ld * CAP;
        if (lo + ld < N && s < min(cnt[ld], CAP))
            ell[(size_t)lo * CAP + idx] = ellLoc[idx];
    }
    if (t < 64 && lo + t < N) {
        int dg = min(cnt[t], CAP);
        cursor[lo + t] = (lo + t) * CAP + dg;
        dinv[lo + t] = rsqrtf(1.0f + (float)cnt[t]);
    }
}

// ================= fallback ELL build (atomic path) =================
__global__ __launch_bounds__(256) void k_cursor_init(int* cursor, int CAP, int n) {
    int i = blockIdx.x * 256 + threadIdx.x;
    if (i < n) cursor[i] = i * CAP;
}

__global__ __launch_bounds__(256) void k_fill_ell(const int* __restrict__ src, const int* __restrict__ dst,
                                                  int* cursor, int* __restrict__ ell, int E,
                                                  int lo, int hi) {
    int i = (blockIdx.x * 256 + threadIdx.x) * 4;
    if (i + 3 < E) {
        int4 d = *(const int4*)(dst + i);
        int4 s = *(const int4*)(src + i);
        if (d.x >= lo && d.x < hi) ell[atomicAdd(&cursor[d.x], 1)] = s.x;
        if (d.y >= lo && d.y < hi) ell[atomicAdd(&cursor[d.y], 1)] = s.y;
        if (d.z >= lo && d.z < hi) ell[atomicAdd(&cursor[d.z], 1)] = s.z;
        if (d.w >= lo && d.w < hi) ell[atomicAdd(&cursor[d.w], 1)] = s.w;
    } else {
        for (int t = i; t < E; ++t) {
            int d = dst[t];
            if (d >= lo && d < hi) ell[atomicAdd(&cursor[d], 1)] = src[t];
        }
    }
}

__global__ __launch_bounds__(256) void k_deg_dinv(const int* __restrict__ cursor, float* dinv, int CAP, int n) {
    int i = blockIdx.x * 256 + threadIdx.x;
    if (i < n) dinv[i] = rsqrtf(1.0f + (float)(cursor[i] - i * CAP));
}

// ---------------- MFMA GEMM: sliced-out[N][64](bf16) = (in[N][K] @ W[K][64] + bb) * dinv[row] ----------------
// Wave w = 16-col tile = output slice w. A frag from global (row-major fp32 x,
// or SLICED bf16 hb: 8-ch span sits inside one 16-ch slice -> 16B contiguous).
// Output written channel-sliced: out16[(w*N + row)*16 + (col&15)].
template <int K, bool AFP32>
__global__ __launch_bounds__(256) void gemm_mfma(const void* __restrict__ in_,
                                                 const unsigned short* __restrict__ Wb,
                                                 const float* __restrict__ bbv,
                                                 const float* __restrict__ dinv,
                                                 unsigned short* __restrict__ out16,  // sliced
                                                 int N) {
    constexpr int NC = K / 32;
    int tid = threadIdx.x;
    int lane = tid & 63, w = tid >> 6;
    int r0 = blockIdx.x * 64;
    int col = w * 16 + (lane & 15);
    int kg = lane >> 4;  // 0..3

    bf16x8 bfrag[NC];
#pragma unroll
    for (int kc = 0; kc < NC; ++kc)
        bfrag[kc] = *(const bf16x8*)(Wb + (size_t)col * K + kc * 32 + kg * 8);
    float bbc = bbv ? bbv[col] : 0.f;

#pragma unroll 1
    for (int rt = 0; rt < 4; ++rt) {
        int arow = r0 + rt * 16 + (lane & 15);
        int arow_c = min(arow, N - 1);
        f32x4 acc = {0.f, 0.f, 0.f, 0.f};
#pragma unroll
        for (int kc = 0; kc < NC; ++kc) {
            bf16x8 afrag;
            if (AFP32) {
                const float* in = (const float*)in_ + (size_t)arow_c * K + kc * 32 + kg * 8;
                float4 lo = *(const float4*)in;
                float4 hi = *(const float4*)(in + 4);
                union { short s[8]; bf16x8 v; } cv;
                cv.s[0] = bfb(lo.x); cv.s[1] = bfb(lo.y); cv.s[2] = bfb(lo.z); cv.s[3] = bfb(lo.w);
                cv.s[4] = bfb(hi.x); cv.s[5] = bfb(hi.y); cv.s[6] = bfb(hi.z); cv.s[7] = bfb(hi.w);
                afrag = cv.v;
            } else {
                // sliced bf16 input: k-offset kc*32+kg*8 -> slice pa, in-slice off (kg&1)*8
                const unsigned short* in = (const unsigned short*)in_;
                int pa = kc * 2 + (kg >> 1);
                afrag = *(const bf16x8*)(in + ((size_t)pa * N + arow_c) * 16 + (kg & 1) * 8);
            }
            acc = __builtin_amdgcn_mfma_f32_16x16x32_bf16(afrag, bfrag[kc], acc, 0, 0, 0);
        }
#pragma unroll
        for (int j = 0; j < 4; ++j) {
            int row = r0 + rt * 16 + kg * 4 + j;
            if (row < N)
                out16[((size_t)w * N + row) * 16 + (lane & 15)] =
                    (unsigned short)bfb((acc[j] + bbc) * dinv[row]);
        }
    }
}

// pack W0[k][c] fp32 -> Wb0[c][k] bf16 (layer 0, K=128)
__global__ void k_packW0(const float* __restrict__ W0, unsigned short* __restrict__ Wb) {
    int c = threadIdx.x;  // 64 threads
    for (int k = 0; k < 128; ++k) Wb[c * 128 + k] = (unsigned short)bfb(W0[k * 64 + c]);
}

// ---------------- ELL pull, channel-sliced: 4 passes of 16 ch ----------------
// Slice table = N*16*2B = 3.2MB -> fits per-XCD L2. Lane cl handles 2 channels
// (4B gather). Wave = 8 groups (nodes) x 8 lanes. 8 edges per batch.
template <bool OUT_BF16>
__global__ __launch_bounds__(256, 4) void k_pull(const int* __restrict__ cursor,
                                                 const int* __restrict__ ell,
                                                 const float* __restrict__ dinv,
                                                 const unsigned* __restrict__ xws8,  // sliced: p*N*8 + n*8 + cl
                                                 const float* __restrict__ bias,
                                                 float* __restrict__ aggf,           // standard [n][64] (layer 2)
                                                 unsigned* __restrict__ aggh8,       // sliced (layers 0,1)
                                                 float* __restrict__ sums, float* __restrict__ sumsq,
                                                 int CAP, int N) {
    int tid = threadIdx.x;
    int lane = tid & 63;
    int g = lane >> 3;
    int cl = lane & 7;
    __shared__ float lsum[256][9], lsq[256][9];

    int slot0 = (blockIdx.x * 4 + (tid >> 6)) * 8 + g;
    int nslots = gridDim.x * 32;

#pragma unroll 1
    for (int p = 0; p < 4; ++p) {
        const unsigned* tab = xws8 + (size_t)p * N * 8;
        float bs0 = bias[p * 16 + cl * 2];
        float bs1 = bias[p * 16 + cl * 2 + 1];
        float sp0 = 0.f, sp1 = 0.f, qp0 = 0.f, qp1 = 0.f;
        for (int n = slot0; n < N; n += nslots) {
            int beg = n * CAP, end = cursor[n];
            int last = end - 1;
            unsigned su = tab[(size_t)n * 8 + cl];   // self (pre-scaled by dinv[n])
            float a0 = bf_lo(su), a1 = bf_hi(su);
            int i = beg;
            for (; i + 8 <= end; i += 8) {  // full batches
                int4 ia = *(const int4*)&ell[i];
                int4 ib = *(const int4*)&ell[i + 4];
                unsigned v0 = tab[(size_t)ia.x * 8 + cl];
                unsigned v1 = tab[(size_t)ia.y * 8 + cl];
                unsigned v2 = tab[(size_t)ia.z * 8 + cl];
                unsigned v3 = tab[(size_t)ia.w * 8 + cl];
                unsigned v4 = tab[(size_t)ib.x * 8 + cl];
                unsigned v5 = tab[(size_t)ib.y * 8 + cl];
                unsigned v6 = tab[(size_t)ib.z * 8 + cl];
                unsigned v7 = tab[(size_t)ib.w * 8 + cl];
                a0 += bf_lo(v0) + bf_lo(v1) + bf_lo(v2) + bf_lo(v3)
                    + bf_lo(v4) + bf_lo(v5) + bf_lo(v6) + bf_lo(v7);
                a1 += bf_hi(v0) + bf_hi(v1) + bf_hi(v2) + bf_hi(v3)
                    + bf_hi(v4) + bf_hi(v5) + bf_hi(v6) + bf_hi(v7);
            }
            if (i < end) {  // tail batch
                int4 ia = *(const int4*)&ell[i];
                int4 ib = *(const int4*)&ell[i + 4];
                int ss[8];
                ss[0] = ia.x; ss[1] = ia.y; ss[2] = ia.z; ss[3] = ia.w;
                ss[4] = ib.x; ss[5] = ib.y; ss[6] = ib.z; ss[7] = ib.w;
#pragma unroll
                for (int k = 0; k < 8; ++k) ss[k] = (i + k <= last) ? ss[k] : 0;
                unsigned vv[8];
#pragma unroll
                for (int k = 0; k < 8; ++k) vv[k] = tab[(size_t)ss[k] * 8 + cl];
#pragma unroll
                for (int k = 0; k < 8; ++k) {
                    if (i + k > last) vv[k] = 0;
                    a0 += bf_lo(vv[k]);
                    a1 += bf_hi(vv[k]);
                }
            }
            float dn = dinv[n];
            float r0 = dn * a0 + bs0;
            float r1 = dn * a1 + bs1;
            sp0 += r0; qp0 += r0 * r0;
            sp1 += r1; qp1 += r1 * r1;
            if (OUT_BF16) {
                aggh8[(size_t)p * N * 8 + (size_t)n * 8 + cl] = pack_bf2(r0, r1);
            } else {
                *(float2*)(aggf + (size_t)n * 64 + p * 16 + cl * 2) = make_float2(r0, r1);
            }
        }
        lsum[tid][p * 2] = sp0;   lsq[tid][p * 2] = qp0;
        lsum[tid][p * 2 + 1] = sp1; lsq[tid][p * 2 + 1] = qp1;
    }
    __syncthreads();
    if (tid < 64) {
        // thread t covers channel t = p*16 + cl*2 + b
        int p = tid >> 4, rem = tid & 15, cl_t = rem >> 1, bq = rem & 1;
        int k = p * 2 + bq;
        float s = 0.f, q = 0.f;
        for (int j = 0; j < 32; ++j) {
            int l = cl_t + 8 * j;
            s += lsum[l][k];
            q += lsq[l][k];
        }
        atomicAdd(&sums[tid], s);
        atomicAdd(&sumsq[tid], q);
    }
}

// ---------------- GraphNorm params + folded next-layer weights (bf16 transposed) + stat zeroing ----------------
__global__ void k_params2(float* __restrict__ sums, float* __restrict__ sumsq,
                          const float* __restrict__ alpha, const float* __restrict__ gamma,
                          const float* __restrict__ beta, const float* __restrict__ W,
                          float* __restrict__ scale, float* __restrict__ shift,
                          unsigned short* __restrict__ Wb, float* __restrict__ bb, int N) {
    __shared__ float ssc[64], ssh[64];
    int c = threadIdx.x;  // 64 threads
    float invN = 1.0f / (float)N;
    float m = sums[c] * invN;
    float ex2 = sumsq[c] * invN;
    float a = alpha[c];
    float var = ex2 - 2.0f * a * m * m + a * a * m * m;
    float sc = gamma[c] * rsqrtf(var + EPS);
    float sh = beta[c] - sc * a * m;
    scale[c] = sc;
    shift[c] = sh;
    ssc[c] = sc;
    ssh[c] = sh;
    sums[c] = 0.f;
    sumsq[c] = 0.f;
    __syncthreads();
    if (W) {
        float acc = 0.f;
        for (int k = 0; k < 64; ++k) {
            float w = W[k * 64 + c];
            Wb[c * 64 + k] = (unsigned short)bfb(ssc[k] * w);  // transposed bf16
            acc += ssh[k] * w;
        }
        bb[c] = acc;
    }
}

__global__ __launch_bounds__(256) void k_final(float* __restrict__ out, const float* __restrict__ scale,
                                               const float* __restrict__ shift, int n64) {
    int i = blockIdx.x * 256 + threadIdx.x;
    if (i < n64) out[i] = scale[i & 63] * out[i] + shift[i & 63];
}

extern "C" void kernel_launch(void* const* d_in, const int* in_sizes, int n_in,
                              void* d_out, int out_size, void* d_ws, size_t ws_size,
                              hipStream_t stream) {
    const float* x     = (const float*)d_in[0];
    const int*   ei    = (const int*)d_in[1];
    const float* W0    = (const float*)d_in[2];
    const float* Wsp   = (const float*)d_in[3];
    const float* b     = (const float*)d_in[4];
    const float* alpha = (const float*)d_in[5];
    const float* gamma = (const float*)d_in[6];
    const float* beta  = (const float*)d_in[7];

    const int N = in_sizes[0] / 128;  // 100000
    const int E = in_sizes[1] / 2;    // 3200000
    const int* src = ei;
    const int* dst = ei + E;

    float* aggf = (float*)d_out;  // N*64 fp32: final-layer agg / output

    const int Na = ((N + 63) / 64) * 64;
    float* ws = (float*)d_ws;
    size_t off = 0;  // in 4-byte units
    float* dinv  = ws + off; off += Na;
    unsigned short* xws = (unsigned short*)(ws + off); off += (size_t)Na * 32;  // sliced 4x[N][16] bf16
    unsigned short* hbs = (unsigned short*)(ws + off); off += (size_t)Na * 32;  // sliced agg (layers 0,1)
    float* sums  = ws + off; off += 64;
    float* sumsq = ws + off; off += 64;
    float* scbuf = ws + off; off += 64;
    float* shbuf = ws + off; off += 64;
    unsigned short* Wb = (unsigned short*)(ws + off); off += 4096;  // 64x128 bf16 max
    float* bbv   = ws + off; off += 64;
    int* cursor  = (int*)(ws + off); off += Na;

    int CAP = 96;
    while (CAP > 72 && (off + (size_t)N * CAP + 8) * 4 > ws_size) CAP -= 8;
    int* ell = (int*)(ws + off); off += (size_t)N * CAP + 8;

    const int n64 = N * 64;
    const int RB = (N + 63) / 64;
    const int NB = (N + 255) / 256;
    const int PB = (N + 63) / 64;  // k_pull: 2 nodes/slot

    // ----- ELL build: scan-based radix partition (no global atomics) -----
    const int NBKT = (N + 63) >> 6;
    const int NSEG = 256;
    int SEG = ((E + NSEG - 1) / NSEG + 3) & ~3;
    const int SCAN_N = NBKT * 256;
    const int NCH = (SCAN_N + 1023) / 1024;
    int* packed    = (int*)xws;
    int* hist      = (int*)hbs;
    int* chunkScan = hist + (size_t)NSEG * NBKT;
    int* chunkTot  = chunkScan + (size_t)NCH * 1024;
    int* chunkBase = chunkTot + NCH;
    bool fast_build = (NBKT <= 2048) && (NCH <= 512) && (N < (1 << 26)) &&
                      ((size_t)E <= (size_t)Na * 32) &&
                      ((size_t)NSEG * NBKT + (size_t)NCH * 1024 + 2 * NCH <= (size_t)Na * 32);

    if (fast_build) {
        k_hist<<<NSEG, 256, 0, stream>>>(dst, hist, E, SEG, NBKT);
        k_scanA<<<NCH, 256, 0, stream>>>(hist, chunkScan, chunkTot, NBKT, SCAN_N);
        k_scanB<<<1, 256, 0, stream>>>(chunkTot, chunkBase, NCH);
        k_scatter_part<<<NSEG, 256, 0, stream>>>(src, dst, chunkScan, chunkBase, packed, E, SEG, NBKT);
        k_ellfill<<<NBKT, 256, 0, stream>>>(packed, chunkScan, chunkBase, ell, cursor, dinv,
                                            CAP, NBKT, N, E);
    } else {
        k_cursor_init<<<NB, 256, 0, stream>>>(cursor, CAP, N);
        const int NCHUNK = 10;
        int cs = (N + NCHUNK - 1) / NCHUNK;
        const int EB4 = (E / 4 + 255) / 256;
        for (int c = 0; c < NCHUNK; ++c) {
            int lo = c * cs, hi = min(N, lo + cs);
            k_fill_ell<<<EB4, 256, 0, stream>>>(src, dst, cursor, ell, E, lo, hi);
        }
        k_deg_dinv<<<NB, 256, 0, stream>>>(cursor, dinv, CAP, N);
    }

    hipMemsetAsync(sums, 0, 128 * sizeof(float), stream);
    k_packW0<<<1, 64, 0, stream>>>(W0, Wb);

    // ----- 3 layers -----
    for (int layer = 0; layer < 3; ++layer) {
        if (layer == 0) {
            gemm_mfma<128, true><<<RB, 256, 0, stream>>>(x, Wb, nullptr, dinv, xws, N);
        } else {
            gemm_mfma<64, false><<<RB, 256, 0, stream>>>(hbs, Wb, bbv, dinv, xws, N);
        }
        if (layer < 2) {
            k_pull<true><<<PB, 256, 0, stream>>>(cursor, ell, dinv, (const unsigned*)xws,
                                                 b + layer * 64, nullptr, (unsigned*)hbs,
                                                 sums, sumsq, CAP, N);
        } else {
            k_pull<false><<<PB, 256, 0, stream>>>(cursor, ell, dinv, (const unsigned*)xws,
                                                  b + layer * 64, aggf, nullptr,
                                                  sums, sumsq, CAP, N);
        }
        const float* Wnext = (layer < 2) ? (Wsp + (size_t)layer * 64 * 64) : nullptr;
        k_params2<<<1, 64, 0, stream>>>(sums, sumsq, alpha + layer * 64, gamma + layer * 64,
                                        beta + layer * 64, Wnext, scbuf, shbuf, Wb, bbv, N);
    }
    k_final<<<(n64 + 255) / 256, 256, 0, stream>>>(aggf, scbuf, shbuf, n64);
}

// Round 19
// 386.650 us; speedup vs baseline: 1.4974x; 1.4974x over previous
//
#include <hip/hip_runtime.h>
#include <hip/hip_bf16.h>

// GraphStack: 3x (GCNConv -> GraphNorm), N=100000, E=3.2M, D_IN=128, C=64.
//
// Round 19: REVERT to round 17 (best: 386us). Round-18 channel slicing
// falsified: 32B slice-row gathers still fetch 128B lines (4x over-fetch/pass)
// and unsynced in-kernel slice loop kept 2-3 slices live per XCD L2 ->
// FETCH rose 165->345MB, pull 75->144us. The unsliced 128B-row gather
// consumes its cache line exactly and is within ~15% of the L2/L3 random
// gather ceiling (survived MLP/occupancy/work-steal/slicing attacks).
//
// Structure: MFMA gemms (LDS-free, bf16), scan-based ELL build (no global
// atomics), 8-lane-group ELL pull (2 nodes/slot), k_params2 fusion,
// bf16 agg for layers 0/1. d_out (N*64 f32) is the final agg buffer.

#define EPS 1e-5f

typedef __attribute__((ext_vector_type(8))) short bf16x8;
typedef __attribute__((ext_vector_type(4))) float f32x4;

__device__ __forceinline__ float bf_lo(unsigned u) {
    union { unsigned u; float f; } c; c.u = u << 16; return c.f;
}
__device__ __forceinline__ float bf_hi(unsigned u) {
    union { unsigned u; float f; } c; c.u = u & 0xffff0000u; return c.f;
}
__device__ __forceinline__ unsigned pack_bf2(float a, float b) {
    union { __hip_bfloat16 h; unsigned short u; } ca, cb;
    ca.h = __float2bfloat16(a);
    cb.h = __float2bfloat16(b);
    return (unsigned)ca.u | ((unsigned)cb.u << 16);
}
__device__ __forceinline__ short bfb(float f) {
    union { __hip_bfloat16 h; short s; } u; u.h = __float2bfloat16(f); return u.s;
}

// ================= scan-based ELL build =================
__global__ __launch_bounds__(256) void k_hist(const int* __restrict__ dst, int* __restrict__ hist,
                                              int E, int SEG, int NBKT) {
    __shared__ int h[2048];
    int t = threadIdx.x;
    for (int b = t; b < NBKT; b += 256) h[b] = 0;
    __syncthreads();
    int i0 = blockIdx.x * SEG, i1 = min(E, i0 + SEG);
    for (int i = i0 + t * 4; i < i1; i += 1024) {
        if (i + 3 < i1) {
            int4 d = *(const int4*)(dst + i);
            atomicAdd(&h[d.x >> 6], 1);
            atomicAdd(&h[d.y >> 6], 1);
            atomicAdd(&h[d.z >> 6], 1);
            atomicAdd(&h[d.w >> 6], 1);
        } else {
            for (int q = i; q < i1; ++q) atomicAdd(&h[dst[q] >> 6], 1);
        }
    }
    __syncthreads();
    for (int b = t; b < NBKT; b += 256) hist[blockIdx.x * NBKT + b] = h[b];
}

__global__ __launch_bounds__(256) void k_scanA(const int* __restrict__ hist, int* __restrict__ chunkScan,
                                               int* __restrict__ chunkTot, int NBKT, int SCAN_N) {
    __shared__ int ls[256];
    int t = threadIdx.x;
    int base = blockIdx.x * 1024 + t * 4;
    int v[4];
#pragma unroll
    for (int j = 0; j < 4; ++j) {
        int l = base + j;
        v[j] = 0;
        if (l < SCAN_N) {
            int blk = l & 255, bkt = l >> 8;
            v[j] = hist[blk * NBKT + bkt];
        }
    }
    int s = v[0] + v[1] + v[2] + v[3];
    ls[t] = s;
    __syncthreads();
    for (int off = 1; off < 256; off <<= 1) {
        int val = (t >= off) ? ls[t - off] : 0;
        __syncthreads();
        ls[t] += val;
        __syncthreads();
    }
    int run = ls[t] - s;
#pragma unroll
    for (int j = 0; j < 4; ++j) {
        chunkScan[base + j] = run;
        run += v[j];
    }
    if (t == 255) chunkTot[blockIdx.x] = ls[255];
}

__global__ void k_scanB(const int* __restrict__ chunkTot, int* __restrict__ chunkBase, int NCH) {
    __shared__ int s[512];
    int t = threadIdx.x;
    s[t] = (t < NCH) ? chunkTot[t] : 0;
    s[t + 256] = (t + 256 < NCH) ? chunkTot[t + 256] : 0;
    __syncthreads();
    for (int off = 1; off < 512; off <<= 1) {
        int a0 = (t >= off) ? s[t - off] : 0;
        int a1 = (t + 256 >= off) ? s[t + 256 - off] : 0;
        __syncthreads();
        s[t] += a0;
        s[t + 256] += a1;
        __syncthreads();
    }
    if (t < NCH) chunkBase[t] = t ? s[t - 1] : 0;
    if (t + 256 < NCH) chunkBase[t + 256] = s[t + 255];
}

__global__ __launch_bounds__(256) void k_scatter_part(const int* __restrict__ src, const int* __restrict__ dst,
                                                      const int* __restrict__ chunkScan,
                                                      const int* __restrict__ chunkBase,
                                                      int* __restrict__ packed, int E, int SEG, int NBKT) {
    __shared__ int cur[2048];
    int blk = blockIdx.x, t = threadIdx.x;
    for (int b = t; b < NBKT; b += 256) {
        int l = b * 256 + blk;
        cur[b] = chunkScan[l] + chunkBase[l >> 10];
    }
    __syncthreads();
    int i0 = blk * SEG, i1 = min(E, i0 + SEG);
    for (int i = i0 + t * 4; i < i1; i += 1024) {
        if (i + 3 < i1) {
            int4 d = *(const int4*)(dst + i);
            int4 s = *(const int4*)(src + i);
            int p;
            p = atomicAdd(&cur[d.x >> 6], 1); packed[p] = (int)(((unsigned)(d.x & 63) << 26) | (unsigned)s.x);
            p = atomicAdd(&cur[d.y >> 6], 1); packed[p] = (int)(((unsigned)(d.y & 63) << 26) | (unsigned)s.y);
            p = atomicAdd(&cur[d.z >> 6], 1); packed[p] = (int)(((unsigned)(d.z & 63) << 26) | (unsigned)s.z);
            p = atomicAdd(&cur[d.w >> 6], 1); packed[p] = (int)(((unsigned)(d.w & 63) << 26) | (unsigned)s.w);
        } else {
            for (int q = i; q < i1; ++q) {
                int dd = dst[q];
                int p = atomicAdd(&cur[dd >> 6], 1);
                packed[p] = (int)(((unsigned)(dd & 63) << 26) | (unsigned)src[q]);
            }
        }
    }
}

__global__ __launch_bounds__(256) void k_ellfill(const int* __restrict__ packed,
                                                 const int* __restrict__ chunkScan,
                                                 const int* __restrict__ chunkBase,
                                                 int* __restrict__ ell, int* __restrict__ cursor,
                                                 float* __restrict__ dinv,
                                                 int CAP, int NBKT, int N, int E) {
    __shared__ int ellLoc[64 * 96];
    __shared__ int cnt[64];
    int bkt = blockIdx.x, t = threadIdx.x;
    if (t < 64) cnt[t] = 0;
    __syncthreads();
    int l0 = bkt * 256;
    int bs = chunkScan[l0] + chunkBase[l0 >> 10];
    int be = E;
    if (bkt + 1 < NBKT) {
        int l1 = (bkt + 1) * 256;
        be = chunkScan[l1] + chunkBase[l1 >> 10];
    }
    for (int i = bs + t; i < be; i += 256) {
        unsigned p = (unsigned)packed[i];
        int s = (int)(p & 0x03FFFFFFu);
        int ld = (int)(p >> 26);
        int slot = atomicAdd(&cnt[ld], 1);
        if (slot < CAP) ellLoc[ld * CAP + slot] = s;
    }
    __syncthreads();
    int lo = bkt << 6;
    int total = 64 * CAP;
    for (int idx = t; idx < total; idx += 256) {
        int ld = idx / CAP;
        int s = idx - ld * CAP;
        if (lo + ld < N && s < min(cnt[ld], CAP))
            ell[(size_t)lo * CAP + idx] = ellLoc[idx];
    }
    if (t < 64 && lo + t < N) {
        int dg = min(cnt[t], CAP);
        cursor[lo + t] = (lo + t) * CAP + dg;
        dinv[lo + t] = rsqrtf(1.0f + (float)cnt[t]);
    }
}

// ================= fallback ELL build (atomic path) =================
__global__ __launch_bounds__(256) void k_cursor_init(int* cursor, int CAP, int n) {
    int i = blockIdx.x * 256 + threadIdx.x;
    if (i < n) cursor[i] = i * CAP;
}

__global__ __launch_bounds__(256) void k_fill_ell(const int* __restrict__ src, const int* __restrict__ dst,
                                                  int* cursor, int* __restrict__ ell, int E,
                                                  int lo, int hi) {
    int i = (blockIdx.x * 256 + threadIdx.x) * 4;
    if (i + 3 < E) {
        int4 d = *(const int4*)(dst + i);
        int4 s = *(const int4*)(src + i);
        if (d.x >= lo && d.x < hi) ell[atomicAdd(&cursor[d.x], 1)] = s.x;
        if (d.y >= lo && d.y < hi) ell[atomicAdd(&cursor[d.y], 1)] = s.y;
        if (d.z >= lo && d.z < hi) ell[atomicAdd(&cursor[d.z], 1)] = s.z;
        if (d.w >= lo && d.w < hi) ell[atomicAdd(&cursor[d.w], 1)] = s.w;
    } else {
        for (int t = i; t < E; ++t) {
            int d = dst[t];
            if (d >= lo && d < hi) ell[atomicAdd(&cursor[d], 1)] = src[t];
        }
    }
}

__global__ __launch_bounds__(256) void k_deg_dinv(const int* __restrict__ cursor, float* dinv, int CAP, int n) {
    int i = blockIdx.x * 256 + threadIdx.x;
    if (i < n) dinv[i] = rsqrtf(1.0f + (float)(cursor[i] - i * CAP));
}

// ---------------- MFMA GEMM: out[N][64](bf16) = (in[N][K] @ W[K][64] + bb) * dinv[row] ----------------
// Wave = 16-col tile (w*16..+15) x 4 row-tiles of 16. No LDS.
// A frag: row = lane&15 (+tile base), k = 32*kc + 8*(lane>>4) + e  -> 16B global load.
// B frag: col = lane&15 (+tile base), same k            -> 16B from Wb[col][K] (bf16 transposed).
// D frag: col = lane&15, row = (lane>>4)*4 + j  [HW-verified layout].
template <int K, bool AFP32>
__global__ __launch_bounds__(256) void gemm_mfma(const void* __restrict__ in_,
                                                 const unsigned short* __restrict__ Wb,
                                                 const float* __restrict__ bbv,
                                                 const float* __restrict__ dinv,
                                                 __hip_bfloat16* __restrict__ out, int N) {
    constexpr int NC = K / 32;
    int tid = threadIdx.x;
    int lane = tid & 63, w = tid >> 6;
    int r0 = blockIdx.x * 64;
    int col = w * 16 + (lane & 15);
    int kg = lane >> 4;  // 0..3

    // B fragments (per wave col-tile), L1-hot
    bf16x8 bfrag[NC];
#pragma unroll
    for (int kc = 0; kc < NC; ++kc)
        bfrag[kc] = *(const bf16x8*)(Wb + (size_t)col * K + kc * 32 + kg * 8);
    float bbc = bbv ? bbv[col] : 0.f;

#pragma unroll 1
    for (int rt = 0; rt < 4; ++rt) {
        int arow = r0 + rt * 16 + (lane & 15);
        int arow_c = min(arow, N - 1);
        f32x4 acc = {0.f, 0.f, 0.f, 0.f};
#pragma unroll
        for (int kc = 0; kc < NC; ++kc) {
            bf16x8 afrag;
            if (AFP32) {
                const float* in = (const float*)in_ + (size_t)arow_c * K + kc * 32 + kg * 8;
                float4 lo = *(const float4*)in;
                float4 hi = *(const float4*)(in + 4);
                union { short s[8]; bf16x8 v; } cv;
                cv.s[0] = bfb(lo.x); cv.s[1] = bfb(lo.y); cv.s[2] = bfb(lo.z); cv.s[3] = bfb(lo.w);
                cv.s[4] = bfb(hi.x); cv.s[5] = bfb(hi.y); cv.s[6] = bfb(hi.z); cv.s[7] = bfb(hi.w);
                afrag = cv.v;
            } else {
                const unsigned short* in = (const unsigned short*)in_;
                afrag = *(const bf16x8*)(in + (size_t)arow_c * K + kc * 32 + kg * 8);
            }
            acc = __builtin_amdgcn_mfma_f32_16x16x32_bf16(afrag, bfrag[kc], acc, 0, 0, 0);
        }
#pragma unroll
        for (int j = 0; j < 4; ++j) {
            int row = r0 + rt * 16 + kg * 4 + j;
            if (row < N)
                out[(size_t)row * 64 + col] = __float2bfloat16((acc[j] + bbc) * dinv[row]);
        }
    }
}

// pack W0[k][c] fp32 -> Wb0[c][k] bf16 (layer 0, K=128)
__global__ void k_packW0(const float* __restrict__ W0, unsigned short* __restrict__ Wb) {
    int c = threadIdx.x;  // 64 threads
    for (int k = 0; k < 128; ++k) Wb[c * 128 + k] = (unsigned short)bfb(W0[k * 64 + c]);
}

// ---------------- ELL pull: 8-lane group per node, static balanced slots ----------------
template <bool OUT_BF16>
__global__ __launch_bounds__(256, 4) void k_pull(const int* __restrict__ cursor,
                                                 const int* __restrict__ ell,
                                                 const float* __restrict__ dinv,
                                                 const uint4* __restrict__ xwh,  // 8 x uint4 per row
                                                 const float* __restrict__ bias,
                                                 float* __restrict__ aggf,
                                                 __hip_bfloat16* __restrict__ aggh,
                                                 float* __restrict__ sums, float* __restrict__ sumsq,
                                                 int CAP, int N) {
    int tid = threadIdx.x;
    int lane = tid & 63;
    int g = lane >> 3;   // group (node slot) 0..7
    int cl = lane & 7;   // channel slice
    float bs[8];
#pragma unroll
    for (int k = 0; k < 8; ++k) bs[k] = bias[cl * 8 + k];
    float s_acc[8] = {0, 0, 0, 0, 0, 0, 0, 0};
    float q_acc[8] = {0, 0, 0, 0, 0, 0, 0, 0};

    int slot = (blockIdx.x * 4 + (tid >> 6)) * 8 + g;
    int nslots = gridDim.x * 32;
    for (int n = slot; n < N; n += nslots) {
        int beg = n * CAP, end = cursor[n];
        int last = end - 1;
        float acc[8];
        {   // self row (already scaled by dinv[n])
            uint4 v = xwh[(size_t)n * 8 + cl];
            acc[0] = bf_lo(v.x); acc[1] = bf_hi(v.x);
            acc[2] = bf_lo(v.y); acc[3] = bf_hi(v.y);
            acc[4] = bf_lo(v.z); acc[5] = bf_hi(v.z);
            acc[6] = bf_lo(v.w); acc[7] = bf_hi(v.w);
        }
        int i = beg;
        for (; i + 8 <= end; i += 8) {  // full batches: no clamp/cndmask
            int4 ia = *(const int4*)&ell[i];
            int4 ib = *(const int4*)&ell[i + 4];
            uint4 vv[8];
            vv[0] = xwh[(size_t)ia.x * 8 + cl];
            vv[1] = xwh[(size_t)ia.y * 8 + cl];
            vv[2] = xwh[(size_t)ia.z * 8 + cl];
            vv[3] = xwh[(size_t)ia.w * 8 + cl];
            vv[4] = xwh[(size_t)ib.x * 8 + cl];
            vv[5] = xwh[(size_t)ib.y * 8 + cl];
            vv[6] = xwh[(size_t)ib.z * 8 + cl];
            vv[7] = xwh[(size_t)ib.w * 8 + cl];
#pragma unroll
            for (int k = 0; k < 8; ++k) {
                acc[0] += bf_lo(vv[k].x); acc[1] += bf_hi(vv[k].x);
                acc[2] += bf_lo(vv[k].y); acc[3] += bf_hi(vv[k].y);
                acc[4] += bf_lo(vv[k].z); acc[5] += bf_hi(vv[k].z);
                acc[6] += bf_lo(vv[k].w); acc[7] += bf_hi(vv[k].w);
            }
        }
        if (i < end) {  // tail batch (1..7 edges): clamp + zero
            int4 ia = *(const int4*)&ell[i];
            int4 ib = *(const int4*)&ell[i + 4];
            int ss[8];
            ss[0] = ia.x; ss[1] = ia.y; ss[2] = ia.z; ss[3] = ia.w;
            ss[4] = ib.x; ss[5] = ib.y; ss[6] = ib.z; ss[7] = ib.w;
#pragma unroll
            for (int k = 0; k < 8; ++k) ss[k] = (i + k <= last) ? ss[k] : 0;
            uint4 vv[8];
#pragma unroll
            for (int k = 0; k < 8; ++k) vv[k] = xwh[(size_t)ss[k] * 8 + cl];
#pragma unroll
            for (int k = 0; k < 8; ++k) {
                if (i + k > last) { vv[k].x = 0; vv[k].y = 0; vv[k].z = 0; vv[k].w = 0; }
                acc[0] += bf_lo(vv[k].x); acc[1] += bf_hi(vv[k].x);
                acc[2] += bf_lo(vv[k].y); acc[3] += bf_hi(vv[k].y);
                acc[4] += bf_lo(vv[k].z); acc[5] += bf_hi(vv[k].z);
                acc[6] += bf_lo(vv[k].w); acc[7] += bf_hi(vv[k].w);
            }
        }
        float dn = dinv[n];
        float r[8];
#pragma unroll
        for (int k = 0; k < 8; ++k) {
            r[k] = dn * acc[k] + bs[k];
            s_acc[k] += r[k];
            q_acc[k] += r[k] * r[k];
        }
        if (OUT_BF16) {
            uint4 o;
            o.x = pack_bf2(r[0], r[1]);
            o.y = pack_bf2(r[2], r[3]);
            o.z = pack_bf2(r[4], r[5]);
            o.w = pack_bf2(r[6], r[7]);
            *(uint4*)((unsigned short*)aggh + (size_t)n * 64 + cl * 8) = o;
        } else {
            float4* d4 = (float4*)(aggf + (size_t)n * 64 + cl * 8);
            d4[0] = make_float4(r[0], r[1], r[2], r[3]);
            d4[1] = make_float4(r[4], r[5], r[6], r[7]);
        }
    }

    // block-level stats reduce
    __shared__ float lsum[256][9], lsq[256][9];
#pragma unroll
    for (int k = 0; k < 8; ++k) { lsum[tid][k] = s_acc[k]; lsq[tid][k] = q_acc[k]; }
    __syncthreads();
    if (tid < 64) {
        int cl_t = tid >> 3, k_t = tid & 7;
        float s = 0.f, q = 0.f;
        for (int j = 0; j < 32; ++j) {
            int l = cl_t + 8 * j;
            s += lsum[l][k_t];
            q += lsq[l][k_t];
        }
        atomicAdd(&sums[tid], s);
        atomicAdd(&sumsq[tid], q);
    }
}

// ---------------- GraphNorm params + folded next-layer weights (bf16 transposed) + stat zeroing ----------------
__global__ void k_params2(float* __restrict__ sums, float* __restrict__ sumsq,
                          const float* __restrict__ alpha, const float* __restrict__ gamma,
                          const float* __restrict__ beta, const float* __restrict__ W,
                          float* __restrict__ scale, float* __restrict__ shift,
                          unsigned short* __restrict__ Wb, float* __restrict__ bb, int N) {
    __shared__ float ssc[64], ssh[64];
    int c = threadIdx.x;  // 64 threads
    float invN = 1.0f / (float)N;
    float m = sums[c] * invN;
    float ex2 = sumsq[c] * invN;
    float a = alpha[c];
    float var = ex2 - 2.0f * a * m * m + a * a * m * m;
    float sc = gamma[c] * rsqrtf(var + EPS);
    float sh = beta[c] - sc * a * m;
    scale[c] = sc;
    shift[c] = sh;
    ssc[c] = sc;
    ssh[c] = sh;
    sums[c] = 0.f;   // reset stats for next layer's pull
    sumsq[c] = 0.f;
    __syncthreads();
    if (W) {
        float acc = 0.f;
        for (int k = 0; k < 64; ++k) {
            float w = W[k * 64 + c];
            Wb[c * 64 + k] = (unsigned short)bfb(ssc[k] * w);  // transposed bf16
            acc += ssh[k] * w;
        }
        bb[c] = acc;
    }
}

__global__ __launch_bounds__(256) void k_final(float* __restrict__ out, const float* __restrict__ scale,
                                               const float* __restrict__ shift, int n64) {
    int i = blockIdx.x * 256 + threadIdx.x;
    if (i < n64) out[i] = scale[i & 63] * out[i] + shift[i & 63];
}

extern "C" void kernel_launch(void* const* d_in, const int* in_sizes, int n_in,
                              void* d_out, int out_size, void* d_ws, size_t ws_size,
                              hipStream_t stream) {
    const float* x     = (const float*)d_in[0];
    const int*   ei    = (const int*)d_in[1];
    const float* W0    = (const float*)d_in[2];
    const float* Wsp   = (const float*)d_in[3];
    const float* b     = (const float*)d_in[4];
    const float* alpha = (const float*)d_in[5];
    const float* gamma = (const float*)d_in[6];
    const float* beta  = (const float*)d_in[7];

    const int N = in_sizes[0] / 128;  // 100000
    const int E = in_sizes[1] / 2;    // 3200000
    const int* src = ei;
    const int* dst = ei + E;

    float* aggf = (float*)d_out;  // N*64 fp32: final-layer agg / output

    const int Na = ((N + 63) / 64) * 64;
    float* ws = (float*)d_ws;
    size_t off = 0;  // in 4-byte units
    float* dinv  = ws + off; off += Na;
    __hip_bfloat16* xwh = (__hip_bfloat16*)(ws + off); off += (size_t)Na * 32;  // N*64 bf16
    __hip_bfloat16* hb  = (__hip_bfloat16*)(ws + off); off += (size_t)Na * 32;  // N*64 bf16 agg (layers 0,1)
    float* sums  = ws + off; off += 64;
    float* sumsq = ws + off; off += 64;
    float* scbuf = ws + off; off += 64;
    float* shbuf = ws + off; off += 64;
    unsigned short* Wb = (unsigned short*)(ws + off); off += 4096;  // 64x128 bf16 max
    float* bbv   = ws + off; off += 64;
    int* cursor  = (int*)(ws + off); off += Na;

    int CAP = 96;
    while (CAP > 72 && (off + (size_t)N * CAP + 8) * 4 > ws_size) CAP -= 8;
    int* ell = (int*)(ws + off); off += (size_t)N * CAP + 8;

    const int n64 = N * 64;
    const int RB = (N + 63) / 64;
    const int NB = (N + 255) / 256;
    const int PB = (N + 63) / 64;  // k_pull: 2 nodes/slot

    // ----- ELL build: scan-based radix partition (no global atomics) -----
    const int NBKT = (N + 63) >> 6;
    const int NSEG = 256;
    int SEG = ((E + NSEG - 1) / NSEG + 3) & ~3;
    const int SCAN_N = NBKT * 256;
    const int NCH = (SCAN_N + 1023) / 1024;
    int* packed    = (int*)xwh;
    int* hist      = (int*)hb;
    int* chunkScan = hist + (size_t)NSEG * NBKT;
    int* chunkTot  = chunkScan + (size_t)NCH * 1024;
    int* chunkBase = chunkTot + NCH;
    bool fast_build = (NBKT <= 2048) && (NCH <= 512) && (N < (1 << 26)) &&
                      ((size_t)E <= (size_t)Na * 32) &&
                      ((size_t)NSEG * NBKT + (size_t)NCH * 1024 + 2 * NCH <= (size_t)Na * 32);

    if (fast_build) {
        k_hist<<<NSEG, 256, 0, stream>>>(dst, hist, E, SEG, NBKT);
        k_scanA<<<NCH, 256, 0, stream>>>(hist, chunkScan, chunkTot, NBKT, SCAN_N);
        k_scanB<<<1, 256, 0, stream>>>(chunkTot, chunkBase, NCH);
        k_scatter_part<<<NSEG, 256, 0, stream>>>(src, dst, chunkScan, chunkBase, packed, E, SEG, NBKT);
        k_ellfill<<<NBKT, 256, 0, stream>>>(packed, chunkScan, chunkBase, ell, cursor, dinv,
                                            CAP, NBKT, N, E);
    } else {
        k_cursor_init<<<NB, 256, 0, stream>>>(cursor, CAP, N);
        const int NCHUNK = 10;
        int cs = (N + NCHUNK - 1) / NCHUNK;
        const int EB4 = (E / 4 + 255) / 256;
        for (int c = 0; c < NCHUNK; ++c) {
            int lo = c * cs, hi = min(N, lo + cs);
            k_fill_ell<<<EB4, 256, 0, stream>>>(src, dst, cursor, ell, E, lo, hi);
        }
        k_deg_dinv<<<NB, 256, 0, stream>>>(cursor, dinv, CAP, N);
    }

    hipMemsetAsync(sums, 0, 128 * sizeof(float), stream);
    k_packW0<<<1, 64, 0, stream>>>(W0, Wb);

    // ----- 3 layers -----
    for (int layer = 0; layer < 3; ++layer) {
        if (layer == 0) {
            gemm_mfma<128, true><<<RB, 256, 0, stream>>>(x, Wb, nullptr, dinv, xwh, N);
        } else {
            gemm_mfma<64, false><<<RB, 256, 0, stream>>>(hb, Wb, bbv, dinv, xwh, N);
        }
        if (layer < 2) {
            k_pull<true><<<PB, 256, 0, stream>>>(cursor, ell, dinv, (const uint4*)xwh,
                                                 b + layer * 64, nullptr, hb,
                                                 sums, sumsq, CAP, N);
        } else {
            k_pull<false><<<PB, 256, 0, stream>>>(cursor, ell, dinv, (const uint4*)xwh,
                                                  b + layer * 64, aggf, nullptr,
                                                  sums, sumsq, CAP, N);
        }
        const float* Wnext = (layer < 2) ? (Wsp + (size_t)layer * 64 * 64) : nullptr;
        k_params2<<<1, 64, 0, stream>>>(sums, sumsq, alpha + layer * 64, gamma + layer * 64,
                                        beta + layer * 64, Wnext, scbuf, shbuf, Wb, bbv, N);
    }
    k_final<<<(n64 + 255) / 256, 256, 0, stream>>>(aggf, scbuf, shbuf, n64);
}